// Round 1
// baseline (30.337 us; speedup 1.0000x reference)
//
#include <hip/hip_runtime.h>

// Son_swapnet: out[b,i] = -sum_e D[i,e] * o3[b,e], where for edge e=(p,q), p<q:
//   d = x[b,p]*w1[p] - x[b,q]*w1[q]
//   o3 = leaky_relu(sum_k w2[k]*|d|^(k+1), 0.01) * sign(d) * w3[e]
// For node i and any partner j (d = o1[i]-o1[j]):
//   contribution to out[b,i] = -leaky(poly(|d|)) * sign(d) * w3[e(min(i,j),max(i,j))]
// (identical formula whether i is the p or the q end; d==0 contributes 0.)

#define C_NODES 256
#define PAD 67          // 67 ≡ 3 (mod 32): conflict-free LDS for both access patterns
#define BTILE 64        // batches per block (one per lane)

__global__ __launch_bounds__(1024) void son_kernel(
    const float* __restrict__ x, const float* __restrict__ w1,
    const float* __restrict__ w2, const float* __restrict__ w3,
    float* __restrict__ out)
{
    __shared__ float o1t[C_NODES * PAD];   // [channel][batch-lane], padded
    const int t  = threadIdx.x;            // 0..1023
    const int b0 = blockIdx.x * BTILE;

    // ---- stage o1t[c][b] = x[b0+b][c] * w1[c] (coalesced reads, conflict-free writes)
    {
        const int c  = t & 255;
        const int rk = t >> 8;             // 0..3
        const float w1c = w1[c];
        #pragma unroll
        for (int r = 0; r < 16; ++r) {
            const int row = r * 4 + rk;    // 0..63
            o1t[c * PAD + row] = x[(b0 + row) * C_NODES + c] * w1c;
        }
    }
    __syncthreads();

    const int lane = t & 63;               // batch within tile
    const int wave = t >> 6;               // 0..15
    // node index for this wave -- force into SGPR so e / w3[e] become scalar
    const int iu = __builtin_amdgcn_readfirstlane(blockIdx.y * 16 + wave);

    const float c0 = w2[0], c1 = w2[1], c2 = w2[2], c3 = w2[3];
    const float oi = o1t[iu * PAD + lane];
    float acc = 0.f;

    // ---- phase 1: j < iu, edge (j, iu): e = j*255 - j(j-1)/2 + iu - j - 1
    //      e starts at iu-1, increments by 254-j
    int e = iu - 1;
    #pragma unroll 4
    for (int j = 0; j < iu; ++j) {
        const float d = oi - o1t[j * PAD + lane];
        const float a = fabsf(d);
        const float poly = a * __builtin_fmaf(a,
                              __builtin_fmaf(a,
                                __builtin_fmaf(a, c3, c2), c1), c0);
        const float lr = fmaxf(poly, 0.01f * poly);   // leaky_relu, branchless
        const float v  = lr * w3[e];                  // w3[e] wave-uniform -> s_load
        acc += (d > 0.f) ? -v : v;                    // d==0 -> v==0, safe
        e += 254 - j;
    }

    // ---- phase 2: j > iu, edge (iu, j): e = base + j
    const int base = iu * 255 - (iu * (iu - 1)) / 2 - iu - 1;
    #pragma unroll 4
    for (int j = iu + 1; j < C_NODES; ++j) {
        const float d = oi - o1t[j * PAD + lane];
        const float a = fabsf(d);
        const float poly = a * __builtin_fmaf(a,
                              __builtin_fmaf(a,
                                __builtin_fmaf(a, c3, c2), c1), c0);
        const float lr = fmaxf(poly, 0.01f * poly);
        const float v  = lr * w3[base + j];
        acc += (d > 0.f) ? -v : v;
    }

    out[(b0 + lane) * C_NODES + iu] = acc;
}

extern "C" void kernel_launch(void* const* d_in, const int* in_sizes, int n_in,
                              void* d_out, int out_size, void* d_ws, size_t ws_size,
                              hipStream_t stream) {
    const float* x  = (const float*)d_in[0];
    const float* w1 = (const float*)d_in[1];
    const float* w2 = (const float*)d_in[2];
    const float* w3 = (const float*)d_in[3];
    float* out = (float*)d_out;

    const int B = in_sizes[0] / C_NODES;       // 1024
    dim3 grid(B / BTILE, C_NODES / 16);        // (16 batch groups, 16 node blocks)
    son_kernel<<<grid, 1024, 0, stream>>>(x, w1, w2, w3, out);
}

// Round 2
// 21.653 us; speedup vs baseline: 1.4011x; 1.4011x over previous
//
#include <hip/hip_runtime.h>

// Son_swapnet: out[b,i] = sum_j -sign(d)*leaky(poly(|d|))*w3[e(i,j)],
//   d = x[b,i]*w1[i] - x[b,j]*w1[j]
// Identity used: with t3 = c0 + |d|(c1 + |d|(c2 + |d|c3)),  poly = |d|*t3,
//   -sign(d)*leaky(poly)*w3 = d*t3*(t3>0 ? 1 : 0.01)*(-w3)
// j==i contributes exactly 0 (d==0), so the j-loop is uniform over all 256.

#define C_NODES 256
#define BT      64      // batch rows per block (one per lane)
#define PADC    260     // row stride (words): 16B-aligned, bank-shift 4 per row
#define NW      8       // waves (= nodes) per block

__global__ __launch_bounds__(512, 4) void son_kernel(
    const float* __restrict__ x, const float* __restrict__ w1,
    const float* __restrict__ w2, const float* __restrict__ w3,
    float* __restrict__ out)
{
    __shared__ __align__(16) float o1t[BT * PADC];        // [batch][channel]
    __shared__ __align__(16) float wrow[NW * C_NODES];    // [wave][j] = -w3[e(i,j)]

    const int t    = threadIdx.x;
    const int lane = t & 63;
    const int w    = t >> 6;                              // 0..7
    const int b0   = blockIdx.x * BT;
    const int i    = __builtin_amdgcn_readfirstlane(blockIdx.y * NW + w);

    // ---- stage o1t[b][c] = x[b0+b][c] * w1[c]  (float4, coalesced)
    {
        const int c4 = lane * 4;
        const float4 w1v = *(const float4*)&w1[c4];
        #pragma unroll
        for (int rr = 0; rr < BT / NW; ++rr) {
            const int row = w + NW * rr;
            const float4 xv = *(const float4*)&x[(b0 + row) * C_NODES + c4];
            float4 o;
            o.x = xv.x * w1v.x; o.y = xv.y * w1v.y;
            o.z = xv.z * w1v.z; o.w = xv.w * w1v.w;
            *(float4*)&o1t[row * PADC + c4] = o;
        }
    }

    // ---- stage wrow[w][j] = -w3[e(i,j)] for this wave's node (L2-resident gather)
    {
        const int j0 = lane * 4;
        float4 wv;
        #pragma unroll
        for (int k = 0; k < 4; ++k) {
            const int j = j0 + k;
            const int p = (i < j) ? i : j;
            const int q = (i < j) ? j : i;
            const int e = (i == j) ? 0 : (p * (511 - p)) / 2 + q - p - 1;
            ((float*)&wv)[k] = -w3[e];
        }
        *(float4*)&wrow[w * C_NODES + j0] = wv;
    }
    __syncthreads();

    const float c0 = w2[0], c1 = w2[1], c2 = w2[2], c3 = w2[3];
    const float oi = o1t[lane * PADC + i];
    float acc = 0.f;

    #pragma unroll 4
    for (int jg = 0; jg < C_NODES / 4; ++jg) {
        const float4 ov = *(const float4*)&o1t[lane * PADC + 4 * jg];  // 4 partners
        const float4 wv = *(const float4*)&wrow[w * C_NODES + 4 * jg]; // uniform bcast
        #pragma unroll
        for (int k = 0; k < 4; ++k) {
            const float oj = ((const float*)&ov)[k];
            const float wk = ((const float*)&wv)[k];
            const float d  = oi - oj;
            const float a  = fabsf(d);
            const float t3 = __builtin_fmaf(a,
                               __builtin_fmaf(a,
                                 __builtin_fmaf(a, c3, c2), c1), c0);
            const float u   = d * t3;
            const float sel = (t3 > 0.f) ? 1.0f : 0.01f;
            acc = __builtin_fmaf(u * sel, wk, acc);
        }
    }

    out[(b0 + lane) * C_NODES + i] = acc;
}

extern "C" void kernel_launch(void* const* d_in, const int* in_sizes, int n_in,
                              void* d_out, int out_size, void* d_ws, size_t ws_size,
                              hipStream_t stream) {
    const float* x  = (const float*)d_in[0];
    const float* w1 = (const float*)d_in[1];
    const float* w2 = (const float*)d_in[2];
    const float* w3 = (const float*)d_in[3];
    float* out = (float*)d_out;

    const int B = in_sizes[0] / C_NODES;          // 1024
    dim3 grid(B / BT, C_NODES / NW);              // 16 x 32 = 512 blocks = 2/CU
    son_kernel<<<grid, 512, 0, stream>>>(x, w1, w2, w3, out);
}